// Round 1
// 678.383 us; speedup vs baseline: 1.2022x; 1.2022x over previous
//
#include <hip/hip_runtime.h>
#include <hip/hip_bf16.h>
#include <stdint.h>

// Problem constants (fixed by the reference)
#define VOCAB  100000
#define EDIM   128
#define HDIM   128
#define T_LEN  1024
#define BATCH  128
#define GDIM   512          // 4*HDIM
#define NROWS  (BATCH*T_LEN) // 131072
#define BN_EPS 1e-3f

using short8 = __attribute__((ext_vector_type(8))) short;  // 8 bf16 (4 VGPR)
using f32x4  = __attribute__((ext_vector_type(4))) float;  // MFMA accumulator

// ---- ws layout (bytes) ----
#define WS_SCALE  0u                          // 128 f32
#define WS_SHIFT  512u                        // 128 f32
#define WS_PSUM   1024u                       // 1024*128 f32
#define WS_PSQ    (WS_PSUM + 524288u)         // 1024*128 f32
#define WS_HCAT   (WS_PSQ + 524288u)          // 128*256 f32
#define WS_FRAGS  (WS_HCAT + 131072u)         // 2*8*32*64*8 bf16 = 524288 B
#define WS_XN     (WS_FRAGS + 524288u)        // 131072*128 bf16 = 33554432 B
// total ~35.3 MB

__device__ __forceinline__ short f2bf(float f) {  // fp32 -> bf16 RNE
    uint32_t u = __float_as_uint(f);
    return (short)((u + 0x7fffu + ((u >> 16) & 1u)) >> 16);
}

#define LOG2E 1.4426950408889634f
// sigmoid/tanh via native v_exp_f32 (exp2) + v_rcp_f32 (~1 ulp; h is bf16 anyway).
// Avoids the 7-9 instr correctly-rounded f32 divide sequence per call.
__device__ __forceinline__ float sigm2(float x) {
    return __builtin_amdgcn_rcpf(1.f + exp2f(x * (-LOG2E)));
}
__device__ __forceinline__ float tanh2(float x) {
    return 1.f - 2.f * __builtin_amdgcn_rcpf(1.f + exp2f(x * (2.f * LOG2E)));
}

// LDS-only barrier: do NOT drain vmcnt (in-flight global prefetches are
// register loads, compiler tracks their deps). __syncthreads would emit
// s_waitcnt vmcnt(0) and serialize L2/HBM latency into the recurrence.
#define BAR() asm volatile("s_waitcnt lgkmcnt(0)\n\ts_barrier" ::: "memory")

// ---------------- K1a: BN1 partial sums (per-feature over B*T) ----------------
__global__ void k_bn1_partial(const int* __restrict__ ids,
                              const float* __restrict__ tab,
                              float* __restrict__ psum, float* __restrict__ psq) {
    __shared__ float ls[256], lq[256];
    int f = threadIdx.x & 127, rr = threadIdx.x >> 7;
    int r0 = blockIdx.x * 128;
    float s = 0.f, q = 0.f;
    for (int r = rr; r < 128; r += 2) {
        int id = ids[r0 + r];
        float v = tab[(size_t)id * EDIM + f];
        s += v; q += v * v;
    }
    ls[threadIdx.x] = s; lq[threadIdx.x] = q;
    __syncthreads();
    if (threadIdx.x < 128) {
        psum[blockIdx.x * 128 + f] = ls[f] + ls[f + 128];
        psq [blockIdx.x * 128 + f] = lq[f] + lq[f + 128];
    }
}

// ---------------- K1b: finalize BN1 -> scale/shift ----------------
__global__ void k_bn1_final(const float* __restrict__ psum, const float* __restrict__ psq,
                            const float* __restrict__ gamma, const float* __restrict__ beta,
                            float* __restrict__ scale, float* __restrict__ shift) {
    int f = threadIdx.x;  // 128 threads
    float s = 0.f, q = 0.f;
    for (int p = 0; p < 1024; ++p) { s += psum[p * 128 + f]; q += psq[p * 128 + f]; }
    const float inv_n = 1.0f / (float)NROWS;
    float m  = s * inv_n;
    float v  = q * inv_n - m * m;
    float sc = gamma[f] * rsqrtf(v + BN_EPS);
    scale[f] = sc;
    shift[f] = beta[f] - m * sc;
}

// ---------------- K2: embed gather + BN1 apply -> bf16 xn ----------------
__global__ void k_embed_norm(const int* __restrict__ ids,
                             const float* __restrict__ tab,
                             const float* __restrict__ scale,
                             const float* __restrict__ shift,
                             short* __restrict__ xn) {
    int gid = blockIdx.x * blockDim.x + threadIdx.x;  // 131072*16
    int row = gid >> 4, seg = gid & 15;
    int id  = ids[row];
    const float* src = tab + (size_t)id * EDIM + seg * 8;
    short8 out;
#pragma unroll
    for (int j = 0; j < 8; ++j) {
        float v = scale[seg * 8 + j] * src[j] + shift[seg * 8 + j];
        out[j] = f2bf(v);
    }
    *(short8*)(xn + (size_t)row * EDIM + seg * 8) = out;
}

// ---------------- K1c: prepack [W;U] into per-lane MFMA B-fragments ----------------
// frag id f = s*16 + gate*4 + kc   (s: 0=W, 1=U)
// B[k = 32*kc + 8*(l>>4) + j][col = 128*gate + 16*w + (l&15)]
__global__ void k_prepack(const float* __restrict__ Wf, const float* __restrict__ Uf,
                          const float* __restrict__ Wb, const float* __restrict__ Ub,
                          short* __restrict__ frags) {
    int gid = blockIdx.x * blockDim.x + threadIdx.x;  // 32768
    int l  = gid & 63;
    int f  = (gid >> 6) & 31;
    int w  = (gid >> 11) & 7;
    int d  = gid >> 14;
    int s    = f >> 4;
    int gate = (f >> 2) & 3;
    int kc   = f & 3;
    const float* M = s ? (d ? Ub : Uf) : (d ? Wb : Wf);
    int rbase = 32 * kc + 8 * (l >> 4);
    int col   = 128 * gate + 16 * w + (l & 15);
    short8 out;
#pragma unroll
    for (int j = 0; j < 8; ++j) out[j] = f2bf(M[(size_t)(rbase + j) * GDIM + col]);
    *(short8*)(frags + (size_t)gid * 8) = out;
}

#define MFMA(A, B, C) __builtin_amdgcn_mfma_f32_16x16x32_bf16((A), (B), (C), 0, 0, 0)
#define S8(x) __builtin_bit_cast(short8, x)

// ---------------- K4: the recurrence. One WG = one (direction, batch row). ----------------
// All hot-loop state in NAMED scalars so the register allocator cannot demote:
//  - 16 named U-frags (64 VGPR) resident across the whole kernel
//  - 16 named W-frags reloaded per chunk from L2 (J=4..7), consumed J=8..11 (off critical path)
//  - xW hoisted per 16-step chunk into double-buffered LDS plane (M=16 rows = timesteps)
//  - serial step = 16 U*h MFMAs + in-register cell update, one LDS-only barrier
//  - accumulators a0..a3 loop-persistent; only element 0 consumed, elems 1-3 carry garbage
__global__ void __launch_bounds__(512, 2)
k_lstm(const int* __restrict__ ids,
       const short* __restrict__ xn,
       const short* __restrict__ frags,
       const float* __restrict__ bf_, const float* __restrict__ bb_,
       float* __restrict__ hcat) {
    const int d   = blockIdx.x >> 7;
    const int b   = blockIdx.x & 127;
    const int tid = threadIdx.x;
    const int w   = tid >> 6, l = tid & 63, g = l >> 4, li = l & 15;

    __shared__ float xg_lds[2][16][512];           // 64 KB: gate pre-acts per chunk
    __shared__ __align__(16) short h_s[2][HDIM];   // bf16 h, ping-pong
    __shared__ unsigned char m_s[T_LEN];

    const short8* wsrc = (const short8*)frags + (size_t)(d * 8 + w) * 32 * 64 + l;

    // U frags: NAMED, loaded once. u{gate}{kc} = wsrc[(16+gate*4+kc)*64]
    short8 u00 = wsrc[(16+0)*64],  u01 = wsrc[(16+1)*64],  u02 = wsrc[(16+2)*64],  u03 = wsrc[(16+3)*64];
    short8 u10 = wsrc[(16+4)*64],  u11 = wsrc[(16+5)*64],  u12 = wsrc[(16+6)*64],  u13 = wsrc[(16+7)*64];
    short8 u20 = wsrc[(16+8)*64],  u21 = wsrc[(16+9)*64],  u22 = wsrc[(16+10)*64], u23 = wsrc[(16+11)*64];
    short8 u30 = wsrc[(16+12)*64], u31 = wsrc[(16+13)*64], u32 = wsrc[(16+14)*64], u33 = wsrc[(16+15)*64];

    // W frags: NAMED, refreshed per chunk (also used in prologue)
    short8 wq00 = wsrc[0*64],  wq01 = wsrc[1*64],  wq02 = wsrc[2*64],  wq03 = wsrc[3*64];
    short8 wq10 = wsrc[4*64],  wq11 = wsrc[5*64],  wq12 = wsrc[6*64],  wq13 = wsrc[7*64];
    short8 wq20 = wsrc[8*64],  wq21 = wsrc[9*64],  wq22 = wsrc[10*64], wq23 = wsrc[11*64];
    short8 wq30 = wsrc[12*64], wq31 = wsrc[13*64], wq32 = wsrc[14*64], wq33 = wsrc[15*64];

    const float* bias = d ? bb_ : bf_;
    const float bia0 = bias[0*128 + w*16 + li];
    const float bia1 = bias[1*128 + w*16 + li];
    const float bia2 = bias[2*128 + w*16 + li];
    const float bia3 = bias[3*128 + w*16 + li];

    {
        const int* idrow = ids + b * T_LEN;
        m_s[tid]       = idrow[tid] != 0;
        m_s[tid + 512] = idrow[tid + 512] != 0;
    }
    if (tid < HDIM) h_s[0][tid] = 0;
    float c_reg = 0.f, h_reg = 0.f;

    float* const xgw = &xg_lds[0][0][0] + w * 16 + li;   // per-thread xg base (col w*16+li)

    // gather A-frags (named) for a chunk: lane l -> x[step 16c+li][k=32kc+8g+j]
    uint4 ga0, ga1, ga2, ga3;
#define GATHER(C_) { \
        int s0_ = 16 * (C_) + li; \
        int p_  = d ? (T_LEN - 1 - s0_) : s0_; \
        const uint4* gb_ = (const uint4*)xn + (size_t)(b * T_LEN + p_) * 16; \
        ga0 = gb_[g]; ga1 = gb_[4 + g]; ga2 = gb_[8 + g]; ga3 = gb_[12 + g]; \
    }

    // xW for one gate: 4 MFMAs (A rows = 16 timesteps), store D rows to xg plane
#define XWGATE(GG, W0, W1, W2, W3, BIA, XGBASE) { \
        f32x4 ax = {(BIA), (BIA), (BIA), (BIA)}; \
        ax = MFMA(S8(ga0), W0, ax); \
        ax = MFMA(S8(ga1), W1, ax); \
        ax = MFMA(S8(ga2), W2, ax); \
        ax = MFMA(S8(ga3), W3, ax); \
        float* dst_ = (XGBASE) + (GG) * 128; \
        dst_[(4*g+0)*512] = ax[0]; dst_[(4*g+1)*512] = ax[1]; \
        dst_[(4*g+2)*512] = ax[2]; dst_[(4*g+3)*512] = ax[3]; \
    }

    // ---- prologue: compute chunk 0's xg into buffer 0 ----
    GATHER(0);
    XWGATE(0, wq00, wq01, wq02, wq03, bia0, xgw);
    XWGATE(1, wq10, wq11, wq12, wq13, bia1, xgw);
    XWGATE(2, wq20, wq21, wq22, wq23, bia2, xgw);
    XWGATE(3, wq30, wq31, wq32, wq33, bia3, xgw);
    __syncthreads();

    float xa0, xa1, xa2, xa3, xb0, xb1, xb2, xb3;
    int   ma, mb;
    xa0 = xgw[0]; xa1 = xgw[128]; xa2 = xgw[256]; xa3 = xgw[384];
    ma  = m_s[d ? (T_LEN - 1) : 0];

    // Persistent accumulators: only element 0 is ever consumed; elements 1-3
    // accumulate stale partials across steps (never read, no traps).
    f32x4 a0 = {0.f,0.f,0.f,0.f}, a1 = {0.f,0.f,0.f,0.f};
    f32x4 a2 = {0.f,0.f,0.f,0.f}, a3 = {0.f,0.f,0.f,0.f};

    // One serial step. J compile-time. XC* = current xg scalars, XN*/MN = prefetch targets.
#define STEP(J, XC0, XC1, XC2, XC3, XN0, XN1, XN2, XN3, MC, MN) { \
        const uint4* hp_ = (const uint4*)(h_s[(J) & 1]); \
        uint4 hf0 = hp_[g], hf1 = hp_[4 + g], hf2 = hp_[8 + g], hf3 = hp_[12 + g]; \
        a0[0] = (XC0); a1[0] = (XC1); a2[0] = (XC2); a3[0] = (XC3); \
        if (c < 63) { \
            if ((J) == 4) { wq00 = wsrc[0*64];  wq01 = wsrc[1*64];  wq02 = wsrc[2*64];  wq03 = wsrc[3*64];  } \
            if ((J) == 5) { wq10 = wsrc[4*64];  wq11 = wsrc[5*64];  wq12 = wsrc[6*64];  wq13 = wsrc[7*64];  } \
            if ((J) == 6) { wq20 = wsrc[8*64];  wq21 = wsrc[9*64];  wq22 = wsrc[10*64]; wq23 = wsrc[11*64]; } \
            if ((J) == 7) { wq30 = wsrc[12*64]; wq31 = wsrc[13*64]; wq32 = wsrc[14*64]; wq33 = wsrc[15*64]; } \
            if ((J) == 8)  XWGATE(0, wq00, wq01, wq02, wq03, bia0, xgw + ((c + 1) & 1) * 8192); \
            if ((J) == 9)  XWGATE(1, wq10, wq11, wq12, wq13, bia1, xgw + ((c + 1) & 1) * 8192); \
            if ((J) == 10) XWGATE(2, wq20, wq21, wq22, wq23, bia2, xgw + ((c + 1) & 1) * 8192); \
            if ((J) == 11) XWGATE(3, wq30, wq31, wq32, wq33, bia3, xgw + ((c + 1) & 1) * 8192); \
        } \
        a0 = MFMA(S8(hf0), u00, a0); a1 = MFMA(S8(hf0), u10, a1); \
        a2 = MFMA(S8(hf0), u20, a2); a3 = MFMA(S8(hf0), u30, a3); \
        a0 = MFMA(S8(hf1), u01, a0); a1 = MFMA(S8(hf1), u11, a1); \
        a2 = MFMA(S8(hf1), u21, a2); a3 = MFMA(S8(hf1), u31, a3); \
        a0 = MFMA(S8(hf2), u02, a0); a1 = MFMA(S8(hf2), u12, a1); \
        a2 = MFMA(S8(hf2), u22, a2); a3 = MFMA(S8(hf2), u32, a3); \
        a0 = MFMA(S8(hf3), u03, a0); a1 = MFMA(S8(hf3), u13, a1); \
        a2 = MFMA(S8(hf3), u23, a2); a3 = MFMA(S8(hf3), u33, a3); \
        if (!((c == 63) && ((J) == 15))) { \
            const float* rb_ = xgw + (((J) < 15) ? (c & 1) : ((c + 1) & 1)) * 8192 \
                                   + (((J) + 1) & 15) * 512; \
            XN0 = rb_[0]; XN1 = rb_[128]; XN2 = rb_[256]; XN3 = rb_[384]; \
            int sn_ = c * 16 + (J) + 1; \
            MN = m_s[d ? (T_LEN - 1 - sn_) : sn_]; \
        } \
        { \
            float gi = a0[0], gf = a1[0], gc = a2[0], go = a3[0]; \
            float si = sigm2(gi); \
            float sf = sigm2(gf); \
            float so = sigm2(go); \
            float tc = tanh2(gc); \
            float cn = sf * c_reg + si * tc; \
            float th = tanh2(cn); \
            float hn = so * th; \
            if (MC) { c_reg = cn; h_reg = hn; } \
            if (l < 16) h_s[((J) + 1) & 1][w * 16 + li] = f2bf(h_reg); \
        } \
        BAR(); \
    }

#pragma unroll 1
    for (int c = 0; c < 64; ++c) {
        if (c < 63) GATHER(c + 1);   // consumed at J=8..11 (xW for chunk c+1)
        STEP(0,  xa0, xa1, xa2, xa3, xb0, xb1, xb2, xb3, ma, mb)
        STEP(1,  xb0, xb1, xb2, xb3, xa0, xa1, xa2, xa3, mb, ma)
        STEP(2,  xa0, xa1, xa2, xa3, xb0, xb1, xb2, xb3, ma, mb)
        STEP(3,  xb0, xb1, xb2, xb3, xa0, xa1, xa2, xa3, mb, ma)
        STEP(4,  xa0, xa1, xa2, xa3, xb0, xb1, xb2, xb3, ma, mb)
        STEP(5,  xb0, xb1, xb2, xb3, xa0, xa1, xa2, xa3, mb, ma)
        STEP(6,  xa0, xa1, xa2, xa3, xb0, xb1, xb2, xb3, ma, mb)
        STEP(7,  xb0, xb1, xb2, xb3, xa0, xa1, xa2, xa3, mb, ma)
        STEP(8,  xa0, xa1, xa2, xa3, xb0, xb1, xb2, xb3, ma, mb)
        STEP(9,  xb0, xb1, xb2, xb3, xa0, xa1, xa2, xa3, mb, ma)
        STEP(10, xa0, xa1, xa2, xa3, xb0, xb1, xb2, xb3, ma, mb)
        STEP(11, xb0, xb1, xb2, xb3, xa0, xa1, xa2, xa3, mb, ma)
        STEP(12, xa0, xa1, xa2, xa3, xb0, xb1, xb2, xb3, ma, mb)
        STEP(13, xb0, xb1, xb2, xb3, xa0, xa1, xa2, xa3, mb, ma)
        STEP(14, xa0, xa1, xa2, xa3, xb0, xb1, xb2, xb3, ma, mb)
        STEP(15, xb0, xb1, xb2, xb3, xa0, xa1, xa2, xa3, mb, ma)
    }

    if (l < 16) hcat[b * 256 + d * 128 + w * 16 + li] = h_reg;  // fp32 final h
}

// ---------------- K5: BN2 + dense(256->10) + softmax ----------------
__global__ void k_head(const float* __restrict__ hcat,
                       const float* __restrict__ gamma2, const float* __restrict__ beta2,
                       const float* __restrict__ Wd, const float* __restrict__ bd,
                       float* __restrict__ out) {
    __shared__ float sc_s[256], sh_s[256];
    __shared__ float logits[BATCH * 10];
    int tid = threadIdx.x;  // 1024
    if (tid < 256) {
        float s = 0.f, q = 0.f;
        for (int bb = 0; bb < BATCH; ++bb) { float v = hcat[bb * 256 + tid]; s += v; q += v * v; }
        float m  = s / (float)BATCH;
        float v  = q / (float)BATCH - m * m;
        float sc = gamma2[tid] * rsqrtf(v + BN_EPS);
        sc_s[tid] = sc;
        sh_s[tid] = beta2[tid] - m * sc;
    }
    __syncthreads();
    {
        int bb = tid >> 3, oq = tid & 7;   // thread -> (batch, out col); oq<2 also covers o=8,9
        float acc0 = bd[oq], acc1 = (oq < 2) ? bd[8 + oq] : 0.f;
        for (int k = 0; k < 256; ++k) {
            float hv = sc_s[k] * hcat[bb * 256 + k] + sh_s[k];
            acc0 += hv * Wd[k * 10 + oq];
            if (oq < 2) acc1 += hv * Wd[k * 10 + 8 + oq];
        }
        logits[bb * 10 + oq] = acc0;
        if (oq < 2) logits[bb * 10 + 8 + oq] = acc1;
    }
    __syncthreads();
    if (tid < BATCH) {
        float lm = -1e30f;
#pragma unroll
        for (int o = 0; o < 10; ++o) lm = fmaxf(lm, logits[tid * 10 + o]);
        float e[10], s = 0.f;
#pragma unroll
        for (int o = 0; o < 10; ++o) { e[o] = __expf(logits[tid * 10 + o] - lm); s += e[o]; }
        float inv = __builtin_amdgcn_rcpf(s);
#pragma unroll
        for (int o = 0; o < 10; ++o) out[tid * 10 + o] = e[o] * inv;
    }
}

extern "C" void kernel_launch(void* const* d_in, const int* in_sizes, int n_in,
                              void* d_out, int out_size, void* d_ws, size_t ws_size,
                              hipStream_t stream) {
    const int*   ids = (const int*)  d_in[0];
    const float* tab = (const float*)d_in[1];
    const float* g1  = (const float*)d_in[2];
    const float* b1  = (const float*)d_in[3];
    const float* Wf  = (const float*)d_in[4];
    const float* Uf  = (const float*)d_in[5];
    const float* bfv = (const float*)d_in[6];
    const float* Wb  = (const float*)d_in[7];
    const float* Ub  = (const float*)d_in[8];
    const float* bbv = (const float*)d_in[9];
    const float* g2  = (const float*)d_in[10];
    const float* b2  = (const float*)d_in[11];
    const float* Wd  = (const float*)d_in[12];
    const float* bd  = (const float*)d_in[13];

    char*  ws    = (char*)d_ws;
    float* scale = (float*)(ws + WS_SCALE);
    float* shift = (float*)(ws + WS_SHIFT);
    float* psum  = (float*)(ws + WS_PSUM);
    float* psq   = (float*)(ws + WS_PSQ);
    float* hcat  = (float*)(ws + WS_HCAT);
    short* fragp = (short*)(ws + WS_FRAGS);
    short* xnp   = (short*)(ws + WS_XN);

    k_bn1_partial<<<1024, 256, 0, stream>>>(ids, tab, psum, psq);
    k_bn1_final  <<<1, 128, 0, stream>>>(psum, psq, g1, b1, scale, shift);
    k_embed_norm <<<8192, 256, 0, stream>>>(ids, tab, scale, shift, xnp);
    k_prepack    <<<128, 256, 0, stream>>>(Wf, Uf, Wb, Ub, fragp);
    k_lstm       <<<256, 512, 0, stream>>>(ids, xnp, fragp, bfv, bbv, hcat);
    k_head       <<<1, 1024, 0, stream>>>(hcat, g2, b2, Wd, bd, (float*)d_out);
}

// Round 2
// 645.242 us; speedup vs baseline: 1.2640x; 1.0514x over previous
//
#include <hip/hip_runtime.h>
#include <hip/hip_bf16.h>
#include <stdint.h>

// Problem constants (fixed by the reference)
#define VOCAB  100000
#define EDIM   128
#define HDIM   128
#define T_LEN  1024
#define BATCH  128
#define GDIM   512          // 4*HDIM
#define NROWS  (BATCH*T_LEN) // 131072
#define BN_EPS 1e-3f

using short8 = __attribute__((ext_vector_type(8))) short;  // 8 bf16 (4 VGPR)
using f32x4  = __attribute__((ext_vector_type(4))) float;  // MFMA accumulator

// ---- ws layout (bytes) ----
#define WS_SCALE  0u                          // 128 f32
#define WS_SHIFT  512u                        // 128 f32
#define WS_PSUM   1024u                       // 1024*128 f32 (reused as mask words after k_bn1_final)
#define WS_PSQ    (WS_PSUM + 524288u)         // 1024*128 f32
#define WS_HCAT   (WS_PSQ + 524288u)          // 128*256 f32
#define WS_FRAGS  (WS_HCAT + 131072u)         // 2*8*32*64*8 bf16 = 524288 B
#define WS_XN     (WS_FRAGS + 524288u)        // 131072*128 bf16 = 33554432 B
// total ~35.3 MB

// activation pre-scale constants folded into weights/biases:
//   sigmoid gates (i,f,o): g' = -log2(e)*g  -> sigm = rcp(1+exp2(g'))
//   tanh gate (c):         g' = 2*log2(e)*g -> tanh = 1-2*rcp(1+exp2(g'))
#define SGI_K (-1.4426950408889634f)
#define SGC_K ( 2.8853900817779268f)

__device__ __forceinline__ short f2bf(float f) {  // fp32 -> bf16 RNE
    uint32_t u = __float_as_uint(f);
    return (short)((u + 0x7fffu + ((u >> 16) & 1u)) >> 16);
}

// LDS-only barrier: do NOT drain vmcnt (in-flight global prefetches are
// register loads, compiler tracks their deps).
#define BAR() asm volatile("s_waitcnt lgkmcnt(0)\n\ts_barrier" ::: "memory")

// ---------------- K1a: BN1 partial sums (per-feature over B*T) ----------------
__global__ void k_bn1_partial(const int* __restrict__ ids,
                              const float* __restrict__ tab,
                              float* __restrict__ psum, float* __restrict__ psq) {
    __shared__ float ls[256], lq[256];
    int f = threadIdx.x & 127, rr = threadIdx.x >> 7;
    int r0 = blockIdx.x * 128;
    float s = 0.f, q = 0.f;
    for (int r = rr; r < 128; r += 2) {
        int id = ids[r0 + r];
        float v = tab[(size_t)id * EDIM + f];
        s += v; q += v * v;
    }
    ls[threadIdx.x] = s; lq[threadIdx.x] = q;
    __syncthreads();
    if (threadIdx.x < 128) {
        psum[blockIdx.x * 128 + f] = ls[f] + ls[f + 128];
        psq [blockIdx.x * 128 + f] = lq[f] + lq[f + 128];
    }
}

// ---------------- K1b: finalize BN1 -> scale/shift ----------------
__global__ void k_bn1_final(const float* __restrict__ psum, const float* __restrict__ psq,
                            const float* __restrict__ gamma, const float* __restrict__ beta,
                            float* __restrict__ scale, float* __restrict__ shift) {
    int f = threadIdx.x;  // 128 threads
    float s = 0.f, q = 0.f;
    for (int p = 0; p < 1024; ++p) { s += psum[p * 128 + f]; q += psq[p * 128 + f]; }
    const float inv_n = 1.0f / (float)NROWS;
    float m  = s * inv_n;
    float v  = q * inv_n - m * m;
    float sc = gamma[f] * rsqrtf(v + BN_EPS);
    scale[f] = sc;
    shift[f] = beta[f] - m * sc;
}

// ---------------- K1m: ballot-pack the sequence mask (1 bit per token) ----------------
__global__ void k_packmask(const int* __restrict__ ids, unsigned long long* __restrict__ mwords) {
    int gid = blockIdx.x * 1024 + threadIdx.x;   // 128 blocks x 1024 = 131072 tokens
    unsigned long long bal = __ballot(ids[gid] != 0);
    if ((threadIdx.x & 63) == 0) mwords[gid >> 6] = bal;
}

// ---------------- K2: embed gather + BN1 apply -> bf16 xn ----------------
__global__ void k_embed_norm(const int* __restrict__ ids,
                             const float* __restrict__ tab,
                             const float* __restrict__ scale,
                             const float* __restrict__ shift,
                             short* __restrict__ xn) {
    int gid = blockIdx.x * blockDim.x + threadIdx.x;  // 131072*16
    int row = gid >> 4, seg = gid & 15;
    int id  = ids[row];
    const float* src = tab + (size_t)id * EDIM + seg * 8;
    short8 out;
#pragma unroll
    for (int j = 0; j < 8; ++j) {
        float v = scale[seg * 8 + j] * src[j] + shift[seg * 8 + j];
        out[j] = f2bf(v);
    }
    *(short8*)(xn + (size_t)row * EDIM + seg * 8) = out;
}

// ---------------- K1c: prepack [W;U] into per-lane MFMA B-fragments ----------------
// frag id f = s*16 + gate*4 + kc   (s: 0=W, 1=U)
// B[k = 32*kc + 8*(l>>4) + j][col = 128*gate + 16*w + (l&15)]
// Weights pre-scaled per-gate for exp2-domain activations.
__global__ void k_prepack(const float* __restrict__ Wf, const float* __restrict__ Uf,
                          const float* __restrict__ Wb, const float* __restrict__ Ub,
                          short* __restrict__ frags) {
    int gid = blockIdx.x * blockDim.x + threadIdx.x;  // 32768
    int l  = gid & 63;
    int f  = (gid >> 6) & 31;
    int w  = (gid >> 11) & 7;
    int d  = gid >> 14;
    int s    = f >> 4;
    int gate = (f >> 2) & 3;
    int kc   = f & 3;
    const float* M = s ? (d ? Ub : Uf) : (d ? Wb : Wf);
    const float gs = (gate == 2) ? SGC_K : SGI_K;
    int rbase = 32 * kc + 8 * (l >> 4);
    int col   = 128 * gate + 16 * w + (l & 15);
    short8 out;
#pragma unroll
    for (int j = 0; j < 8; ++j) out[j] = f2bf(gs * M[(size_t)(rbase + j) * GDIM + col]);
    *(short8*)(frags + (size_t)gid * 8) = out;
}

#define MFMA(A, B, C) __builtin_amdgcn_mfma_f32_16x16x32_bf16((A), (B), (C), 0, 0, 0)
#define S8(x) __builtin_bit_cast(short8, x)

// ---------------- K4: the recurrence. One WG = one (direction, batch row). ----------------
//  - 16 named U-frags + 16 named W-frags RESIDENT (no reloads; ~200 VGPR, 2 waves/SIMD)
//  - xW hoisted per 16-step chunk into double-buffered LDS plane, layout [row][col][gate]
//    (gate-innermost float4 -> one conflict-free ds_read_b128 per step, was 4x 4-way-conflicted b32)
//  - U*h split into two 2-deep MFMA chains (p,q) with zero C -> half the chain latency,
//    xg folded in via scalar adds (kills the per-step acc-elem0 movs)
//  - mask as ballot-packed bits: per chunk one uniform scalar load, per step 2 SALU
//  - h -> bf16 via single v_cvt_pk_bf16_f32 (RNE, bit-identical to f2bf)
__global__ void __launch_bounds__(512, 2)
k_lstm(const short* __restrict__ xn,
       const short* __restrict__ frags,
       const unsigned long long* __restrict__ mwords,
       const float* __restrict__ bf_, const float* __restrict__ bb_,
       float* __restrict__ hcat) {
    const int d   = blockIdx.x >> 7;
    const int b   = blockIdx.x & 127;
    const int tid = threadIdx.x;
    const int w   = tid >> 6, l = tid & 63, g = l >> 4, li = l & 15;

    __shared__ float xg_lds[2][16][512];           // 64 KB: gate pre-acts, [buf][row][col*4+gate]
    __shared__ __align__(16) short h_s[2][HDIM];   // bf16 h, ping-pong

    float* const xgf = &xg_lds[0][0][0];
    float* const xgr = xgf + (w * 16 + li) * 4;    // per-thread read base (col's float4)

    const short8* wsrc = (const short8*)frags + (size_t)(d * 8 + w) * 32 * 64 + l;

    // W frags: NAMED, resident
    short8 wq00 = wsrc[0*64],  wq01 = wsrc[1*64],  wq02 = wsrc[2*64],  wq03 = wsrc[3*64];
    short8 wq10 = wsrc[4*64],  wq11 = wsrc[5*64],  wq12 = wsrc[6*64],  wq13 = wsrc[7*64];
    short8 wq20 = wsrc[8*64],  wq21 = wsrc[9*64],  wq22 = wsrc[10*64], wq23 = wsrc[11*64];
    short8 wq30 = wsrc[12*64], wq31 = wsrc[13*64], wq32 = wsrc[14*64], wq33 = wsrc[15*64];

    // U frags: NAMED, resident
    short8 u00 = wsrc[(16+0)*64],  u01 = wsrc[(16+1)*64],  u02 = wsrc[(16+2)*64],  u03 = wsrc[(16+3)*64];
    short8 u10 = wsrc[(16+4)*64],  u11 = wsrc[(16+5)*64],  u12 = wsrc[(16+6)*64],  u13 = wsrc[(16+7)*64];
    short8 u20 = wsrc[(16+8)*64],  u21 = wsrc[(16+9)*64],  u22 = wsrc[(16+10)*64], u23 = wsrc[(16+11)*64];
    short8 u30 = wsrc[(16+12)*64], u31 = wsrc[(16+13)*64], u32 = wsrc[(16+14)*64], u33 = wsrc[(16+15)*64];

    const float* bias = d ? bb_ : bf_;
    const float bia0 = bias[0*128 + w*16 + li] * SGI_K;
    const float bia1 = bias[1*128 + w*16 + li] * SGI_K;
    const float bia2 = bias[2*128 + w*16 + li] * SGC_K;
    const float bia3 = bias[3*128 + w*16 + li] * SGI_K;

    if (tid < HDIM) h_s[0][tid] = 0;
    float c_reg = 0.f, h_reg = 0.f;

    const f32x4 Z = {0.f, 0.f, 0.f, 0.f};

    // gather A-frags (named) for a chunk: lane l -> x[step 16c+li][k=32kc+8g+j]
    uint4 ga0, ga1, ga2, ga3;
#define GATHER(C_) { \
        int s0_ = 16 * (C_) + li; \
        int p_  = d ? (T_LEN - 1 - s0_) : s0_; \
        const uint4* gb_ = (const uint4*)xn + (size_t)(b * T_LEN + p_) * 16; \
        ga0 = gb_[g]; ga1 = gb_[4 + g]; ga2 = gb_[8 + g]; ga3 = gb_[12 + g]; \
    }

    // xW for one gate: 4 MFMAs (A rows = 16 timesteps), store D rows to [row][col][gate]
#define XWGATE(GG, W0, W1, W2, W3, BIA, BUF) { \
        f32x4 ax = {(BIA), (BIA), (BIA), (BIA)}; \
        ax = MFMA(S8(ga0), W0, ax); \
        ax = MFMA(S8(ga1), W1, ax); \
        ax = MFMA(S8(ga2), W2, ax); \
        ax = MFMA(S8(ga3), W3, ax); \
        float* dst_ = xgf + (BUF) * 8192 + (w * 16 + li) * 4 + (GG); \
        dst_[(4*g+0)*512] = ax[0]; dst_[(4*g+1)*512] = ax[1]; \
        dst_[(4*g+2)*512] = ax[2]; dst_[(4*g+3)*512] = ax[3]; \
    }

    // ---- prologue: compute chunk 0's xg into buffer 0 ----
    GATHER(0);
    XWGATE(0, wq00, wq01, wq02, wq03, bia0, 0);
    XWGATE(1, wq10, wq11, wq12, wq13, bia1, 0);
    XWGATE(2, wq20, wq21, wq22, wq23, bia2, 0);
    XWGATE(3, wq30, wq31, wq32, wq33, bia3, 0);
    __syncthreads();

    float xa0, xa1, xa2, xa3, xb0, xb1, xb2, xb3;
    {
        const f32x4 xv0 = *(const f32x4*)(xgr);
        xa0 = xv0[0]; xa1 = xv0[1]; xa2 = xv0[2]; xa3 = xv0[3];
    }

    // One serial step. J compile-time. XC* = current xg scalars, XN* = prefetch targets.
#define STEP(J, XC0, XC1, XC2, XC3, XN0, XN1, XN2, XN3) { \
        const uint4* hp_ = (const uint4*)(h_s[(J) & 1]); \
        uint4 hf0 = hp_[g], hf1 = hp_[4 + g], hf2 = hp_[8 + g], hf3 = hp_[12 + g]; \
        if (c < 63) { \
            if ((J) == 8)  XWGATE(0, wq00, wq01, wq02, wq03, bia0, ((c + 1) & 1)); \
            if ((J) == 9)  XWGATE(1, wq10, wq11, wq12, wq13, bia1, ((c + 1) & 1)); \
            if ((J) == 10) XWGATE(2, wq20, wq21, wq22, wq23, bia2, ((c + 1) & 1)); \
            if ((J) == 11) XWGATE(3, wq30, wq31, wq32, wq33, bia3, ((c + 1) & 1)); \
        } \
        f32x4 p0 = MFMA(S8(hf0), u00, Z); \
        f32x4 p1 = MFMA(S8(hf0), u10, Z); \
        f32x4 p2 = MFMA(S8(hf0), u20, Z); \
        f32x4 p3 = MFMA(S8(hf0), u30, Z); \
        f32x4 q0 = MFMA(S8(hf2), u02, Z); \
        f32x4 q1 = MFMA(S8(hf2), u12, Z); \
        f32x4 q2 = MFMA(S8(hf2), u22, Z); \
        f32x4 q3 = MFMA(S8(hf2), u32, Z); \
        p0 = MFMA(S8(hf1), u01, p0); \
        p1 = MFMA(S8(hf1), u11, p1); \
        p2 = MFMA(S8(hf1), u21, p2); \
        p3 = MFMA(S8(hf1), u31, p3); \
        q0 = MFMA(S8(hf3), u03, q0); \
        q1 = MFMA(S8(hf3), u13, q1); \
        q2 = MFMA(S8(hf3), u23, q2); \
        q3 = MFMA(S8(hf3), u33, q3); \
        if (!((c == 63) && ((J) == 15))) { \
            const f32x4 xv_ = *(const f32x4*)(xgr + (((J) < 15) ? (c & 1) : ((c + 1) & 1)) * 8192 \
                                                  + (((J) + 1) & 15) * 512); \
            XN0 = xv_[0]; XN1 = xv_[1]; XN2 = xv_[2]; XN3 = xv_[3]; \
        } \
        { \
            float gi = (XC0) + (p0[0] + q0[0]); \
            float gf = (XC1) + (p1[0] + q1[0]); \
            float gc = (XC2) + (p2[0] + q2[0]); \
            float go = (XC3) + (p3[0] + q3[0]); \
            float si = __builtin_amdgcn_rcpf(1.f + exp2f(gi)); \
            float sf = __builtin_amdgcn_rcpf(1.f + exp2f(gf)); \
            float so = __builtin_amdgcn_rcpf(1.f + exp2f(go)); \
            float tc = __builtin_fmaf(-2.f, __builtin_amdgcn_rcpf(1.f + exp2f(gc)), 1.f); \
            float cn = __builtin_fmaf(sf, c_reg, si * tc); \
            float th = __builtin_fmaf(-2.f, __builtin_amdgcn_rcpf(1.f + exp2f(cn * SGC_K)), 1.f); \
            float hn = so * th; \
            if (mb & (1u << (J))) { c_reg = cn; h_reg = hn; } \
            uint32_t pk_; \
            asm("v_cvt_pk_bf16_f32 %0, %1, %2" : "=v"(pk_) : "v"(h_reg), "v"(h_reg)); \
            if (l < 16) h_s[((J) + 1) & 1][w * 16 + li] = (short)pk_; \
        } \
        BAR(); \
    }

#pragma unroll 1
    for (int c = 0; c < 64; ++c) {
        if (c < 63) GATHER(c + 1);   // consumed at J=8..11 (xW for chunk c+1)
        int cc_ = d ? 63 - c : c;
        unsigned long long mw_ = mwords[(size_t)b * 16 + (cc_ >> 2)];
        uint32_t mb = (uint32_t)(mw_ >> ((cc_ & 3) * 16)) & 0xFFFFu;
        if (d) mb = __builtin_bitreverse32(mb) >> 16;
        STEP(0,  xa0, xa1, xa2, xa3, xb0, xb1, xb2, xb3)
        STEP(1,  xb0, xb1, xb2, xb3, xa0, xa1, xa2, xa3)
        STEP(2,  xa0, xa1, xa2, xa3, xb0, xb1, xb2, xb3)
        STEP(3,  xb0, xb1, xb2, xb3, xa0, xa1, xa2, xa3)
        STEP(4,  xa0, xa1, xa2, xa3, xb0, xb1, xb2, xb3)
        STEP(5,  xb0, xb1, xb2, xb3, xa0, xa1, xa2, xa3)
        STEP(6,  xa0, xa1, xa2, xa3, xb0, xb1, xb2, xb3)
        STEP(7,  xb0, xb1, xb2, xb3, xa0, xa1, xa2, xa3)
        STEP(8,  xa0, xa1, xa2, xa3, xb0, xb1, xb2, xb3)
        STEP(9,  xb0, xb1, xb2, xb3, xa0, xa1, xa2, xa3)
        STEP(10, xa0, xa1, xa2, xa3, xb0, xb1, xb2, xb3)
        STEP(11, xb0, xb1, xb2, xb3, xa0, xa1, xa2, xa3)
        STEP(12, xa0, xa1, xa2, xa3, xb0, xb1, xb2, xb3)
        STEP(13, xb0, xb1, xb2, xb3, xa0, xa1, xa2, xa3)
        STEP(14, xa0, xa1, xa2, xa3, xb0, xb1, xb2, xb3)
        STEP(15, xb0, xb1, xb2, xb3, xa0, xa1, xa2, xa3)
    }

    if (l < 16) hcat[b * 256 + d * 128 + w * 16 + li] = h_reg;  // fp32 final h
}

// ---------------- K5: BN2 + dense(256->10) + softmax ----------------
__global__ void k_head(const float* __restrict__ hcat,
                       const float* __restrict__ gamma2, const float* __restrict__ beta2,
                       const float* __restrict__ Wd, const float* __restrict__ bd,
                       float* __restrict__ out) {
    __shared__ float sc_s[256], sh_s[256];
    __shared__ float logits[BATCH * 10];
    int tid = threadIdx.x;  // 1024
    if (tid < 256) {
        float s = 0.f, q = 0.f;
        for (int bb = 0; bb < BATCH; ++bb) { float v = hcat[bb * 256 + tid]; s += v; q += v * v; }
        float m  = s / (float)BATCH;
        float v  = q / (float)BATCH - m * m;
        float sc = gamma2[tid] * rsqrtf(v + BN_EPS);
        sc_s[tid] = sc;
        sh_s[tid] = beta2[tid] - m * sc;
    }
    __syncthreads();
    {
        int bb = tid >> 3, oq = tid & 7;   // thread -> (batch, out col); oq<2 also covers o=8,9
        float acc0 = bd[oq], acc1 = (oq < 2) ? bd[8 + oq] : 0.f;
        for (int k = 0; k < 256; ++k) {
            float hv = sc_s[k] * hcat[bb * 256 + k] + sh_s[k];
            acc0 += hv * Wd[k * 10 + oq];
            if (oq < 2) acc1 += hv * Wd[k * 10 + 8 + oq];
        }
        logits[bb * 10 + oq] = acc0;
        if (oq < 2) logits[bb * 10 + 8 + oq] = acc1;
    }
    __syncthreads();
    if (tid < BATCH) {
        float lm = -1e30f;
#pragma unroll
        for (int o = 0; o < 10; ++o) lm = fmaxf(lm, logits[tid * 10 + o]);
        float e[10], s = 0.f;
#pragma unroll
        for (int o = 0; o < 10; ++o) { e[o] = __expf(logits[tid * 10 + o] - lm); s += e[o]; }
        float inv = __builtin_amdgcn_rcpf(s);
#pragma unroll
        for (int o = 0; o < 10; ++o) out[tid * 10 + o] = e[o] * inv;
    }
}

extern "C" void kernel_launch(void* const* d_in, const int* in_sizes, int n_in,
                              void* d_out, int out_size, void* d_ws, size_t ws_size,
                              hipStream_t stream) {
    const int*   ids = (const int*)  d_in[0];
    const float* tab = (const float*)d_in[1];
    const float* g1  = (const float*)d_in[2];
    const float* b1  = (const float*)d_in[3];
    const float* Wf  = (const float*)d_in[4];
    const float* Uf  = (const float*)d_in[5];
    const float* bfv = (const float*)d_in[6];
    const float* Wb  = (const float*)d_in[7];
    const float* Ub  = (const float*)d_in[8];
    const float* bbv = (const float*)d_in[9];
    const float* g2  = (const float*)d_in[10];
    const float* b2  = (const float*)d_in[11];
    const float* Wd  = (const float*)d_in[12];
    const float* bd  = (const float*)d_in[13];

    char*  ws    = (char*)d_ws;
    float* scale = (float*)(ws + WS_SCALE);
    float* shift = (float*)(ws + WS_SHIFT);
    float* psum  = (float*)(ws + WS_PSUM);
    float* psq   = (float*)(ws + WS_PSQ);
    float* hcat  = (float*)(ws + WS_HCAT);
    short* fragp = (short*)(ws + WS_FRAGS);
    short* xnp   = (short*)(ws + WS_XN);
    unsigned long long* mwords = (unsigned long long*)(ws + WS_PSUM);  // reuse psum after k_bn1_final

    k_bn1_partial<<<1024, 256, 0, stream>>>(ids, tab, psum, psq);
    k_bn1_final  <<<1, 128, 0, stream>>>(psum, psq, g1, b1, scale, shift);
    k_packmask   <<<128, 1024, 0, stream>>>(ids, mwords);   // after bn1_final: overwrites psum region
    k_embed_norm <<<8192, 256, 0, stream>>>(ids, tab, scale, shift, xnp);
    k_prepack    <<<128, 256, 0, stream>>>(Wf, Uf, Wb, Ub, fragp);
    k_lstm       <<<256, 512, 0, stream>>>(xnp, fragp, mwords, bfv, bbv, hcat);
    k_head       <<<1, 1024, 0, stream>>>(hcat, g2, b2, Wd, bd, (float*)d_out);
}